// Round 5
// baseline (185.983 us; speedup 1.0000x reference)
//
#include <hip/hip_runtime.h>
#include <hip/hip_bf16.h>
#include <math.h>

#define NEG_ 16
#define PRED_ 5
#define EPS_ 1e-11f
#define LDW 18    // logit tile row stride (floats)
#define ASTR 72   // gemm LDS tile row stride in shorts (144 B, odd16 -> conflict-free b128)

typedef __attribute__((ext_vector_type(8))) short bf16x8;
typedef __attribute__((ext_vector_type(4))) float f32x4;

static __device__ __forceinline__ unsigned short f2bu(float f) {
  __hip_bfloat16 h = __float2bfloat16(f);
  return *(unsigned short*)&h;
}

// ws layout (bytes):
//   Zp bf16 [16384][256] : 0         rows = (h*16+w)*64+b; rows<2048 (h<2) never touched
//   Cb bf16 [16384][256] : 8388608   rows>=14336 never touched
//   Wb bf16 [5][256][256]: 16777216  TRANSPOSED: Wb[k][o][i] = Wk[k][i][o]
//   Cw bf16 [5][14336][256]: 17432576  projected CONTEXT (Wk^T ctx); rows>=Mk unused per k
//   Lk f32  [5][14336]   : 54132736  tails [Mk,14336) NEVER read -> no memset
// Purity: every read is of data written earlier in this launch.
// out[0] is re-zeroed by prep_all each launch (finalize atomicAdds into it).
//
// score_all: direct-from-global MFMA fragments with ALL chain buffers loaded
// upfront (b0..b4, statically indexed), pinned above the MFMA clusters by
// sched_barrier(0). launch_bounds(256,2) gives the register budget (~220
// VGPR) to hold them -> up to 48 dwordx4 in flight per wave. R4 failed
// because the compiler sank these loads (VGPR=60 proved it); this pins them.

// ---- prep: transpose z/c (+cast) with 128B-coalesced reads AND writes ----
__global__ __launch_bounds__(256) void prep_all(
    const float* __restrict__ z, const float* __restrict__ c,
    const float* __restrict__ Wk,
    unsigned short* __restrict__ Zp, unsigned short* __restrict__ Cb,
    unsigned short* __restrict__ Wb, float* __restrict__ out) {
  __shared__ float tile[32][65];   // [q][p]
  const int t = threadIdx.x;
  if (blockIdx.x == 0 && blockIdx.y == 0 && blockIdx.z == 0 && t == 0)
    out[0] = 0.f;   // total-loss accumulator, replay-safe zeroing
  if (blockIdx.y == 7) {
    // Wk TRANSPOSE (+cast): 5 matrices of 256x256, 32x32 LDS tiles.
    int ib = blockIdx.z * 256 + blockIdx.x;   // 0..511; need 320 = 5 k * 64 tiles
    if (ib < 320) {
      const int k = ib >> 6, tl = ib & 63;
      const int r0 = (tl >> 3) * 32, c0g = (tl & 7) * 32;
      const int tx = t & 31, ty = t >> 5;     // (32,8)
#pragma unroll
      for (int r = 0; r < 32; r += 8)
        tile[ty + r][tx] = Wk[k * 65536 + (r0 + ty + r) * 256 + c0g + tx];
      __syncthreads();
#pragma unroll
      for (int r = 0; r < 32; r += 8)   // Wb[k][o][i] = Wk[k][i][o]
        Wb[k * 65536 + (c0g + ty + r) * 256 + r0 + tx] = f2bu(tile[tx][ty + r]);
    }
    return;
  }
  const float* in = blockIdx.z ? c : z;
  unsigned short* out2 = blockIdx.z ? Cb : Zp;
  const int p0 = blockIdx.x * 64;                          // [0,16384)
  const int q0 = blockIdx.y * 32 + (blockIdx.z ? 0 : 32);  // z:[32,256) c:[0,224)
  const int tx = t & 31, ty = t >> 5;       // (32,8)
#pragma unroll
  for (int r = 0; r < 64; r += 8)
    tile[tx][ty + r] = in[(size_t)(p0 + ty + r) * 256 + q0 + tx];
  __syncthreads();
  const int pp = t & 63, wq = t >> 6;       // (64,4)
#pragma unroll
  for (int r = 0; r < 32; r += 4)
    out2[(size_t)(q0 + wq + r) * 16384 + p0 + pp] = f2bu(tile[wq + r][pp]);
}

// ---- LDS-staged MFMA GEMM: 128x128 tile, BK=64 ----
// Computes Cw_k[m][o] = sum_i Cb[m][i] * Wb_k[o][i] = (Wk^T ctx[m])[o].
__global__ __launch_bounds__(256) void gemm_all(
    const unsigned short* __restrict__ Cb, const unsigned short* __restrict__ Wb,
    unsigned short* __restrict__ Cw) {
  const int kk = blockIdx.z;
  const int Mk = (14 - kk) * 1024;
  const int m0b = blockIdx.y * 128;
  if (m0b >= Mk) return;
  const unsigned short* A = Cb;
  const unsigned short* Wm = Wb + (size_t)kk * 65536;
  unsigned short* Y = Cw + (size_t)kk * 14336 * 256;
  __shared__ unsigned short As[128 * ASTR];
  __shared__ unsigned short Bs[128 * ASTR];
  const int t = threadIdx.x;
  const int wid = t >> 6, lane = t & 63;
  const int wm = wid >> 1, wn = wid & 1;
  const int l15 = lane & 15, quad = lane >> 4;
  const int n0 = blockIdx.x * 128;
  const int srow = t >> 1, shalf = t & 1;
  const unsigned short* ga = A + (size_t)(m0b + srow) * 256 + shalf * 32;
  const unsigned short* gb = Wm + (size_t)(n0 + srow) * 256 + shalf * 32;
  unsigned short* wa = As + srow * ASTR + shalf * 32;
  unsigned short* wb = Bs + srow * ASTR + shalf * 32;
  f32x4 acc[4][4] = {};
  bf16x8 ra[4], rb[4];
#pragma unroll
  for (int cs = 0; cs < 4; ++cs) {
    ra[cs] = *(const bf16x8*)(ga + cs * 8);
    rb[cs] = *(const bf16x8*)(gb + cs * 8);
  }
#pragma unroll
  for (int ki = 0; ki < 4; ++ki) {
    __syncthreads();
#pragma unroll
    for (int cs = 0; cs < 4; ++cs) {
      *(bf16x8*)(wa + cs * 8) = ra[cs];
      *(bf16x8*)(wb + cs * 8) = rb[cs];
    }
    __syncthreads();
    if (ki < 3) {
      const int k1 = (ki + 1) * 64;
#pragma unroll
      for (int cs = 0; cs < 4; ++cs) {
        ra[cs] = *(const bf16x8*)(ga + k1 + cs * 8);
        rb[cs] = *(const bf16x8*)(gb + k1 + cs * 8);
      }
    }
#pragma unroll
    for (int ks = 0; ks < 2; ++ks) {
      bf16x8 af[4], bf[4];
#pragma unroll
      for (int tm = 0; tm < 4; ++tm)
        af[tm] = *(const bf16x8*)(As + (wm * 64 + tm * 16 + l15) * ASTR + ks * 32 + quad * 8);
#pragma unroll
      for (int tn = 0; tn < 4; ++tn)
        bf[tn] = *(const bf16x8*)(Bs + (wn * 64 + tn * 16 + l15) * ASTR + ks * 32 + quad * 8);
#pragma unroll
      for (int tm = 0; tm < 4; ++tm)
#pragma unroll
        for (int tn = 0; tn < 4; ++tn)
          acc[tm][tn] = __builtin_amdgcn_mfma_f32_16x16x32_bf16(
              af[tm], bf[tn], acc[tm][tn], 0, 0, 0);
    }
  }
#pragma unroll
  for (int tm = 0; tm < 4; ++tm)
#pragma unroll
    for (int tn = 0; tn < 4; ++tn)
#pragma unroll
      for (int r = 0; r < 4; ++r)
        Y[(size_t)(m0b + wm * 64 + tm * 16 + quad * 4 + r) * 256 +
          n0 + wn * 64 + tn * 16 + l15] = f2bu(acc[tm][tn][r]);
}

// ---- fused scoring: all-upfront pinned fragment loads, no LDS staging ----
__global__ __launch_bounds__(256, 2) void score_all(
    const unsigned short* __restrict__ Cw, const unsigned short* __restrict__ Zp,
    const int* __restrict__ r1, const int* __restrict__ r2,
    const int* __restrict__ r3, const int* __restrict__ r4,
    const int* __restrict__ r5, float* __restrict__ Lk) {
  __shared__ float L[16 * LDW];
  const int wv = threadIdx.x >> 6, lane = threadIdx.x & 63;
  const int gid = blockIdx.x;
  int kk, base;
  if (gid < 896)       { kk = 0; base = 0; }
  else if (gid < 1728) { kk = 1; base = 896; }
  else if (gid < 2496) { kk = 2; base = 1728; }
  else if (gid < 3200) { kk = 3; base = 2496; }
  else                 { kk = 4; base = 3200; }
  const int Mk = (14 - kk) * 1024;
  const int m0 = (gid - base) * 16;
  const int* ridx = kk == 0 ? r1 : kk == 1 ? r2 : kk == 2 ? r3 : kk == 3 ? r4 : r5;
  const unsigned short* Yc = Cw + (size_t)kk * 14336 * 256;       // projected ctx
  const unsigned short* Z  = Zp + (size_t)(kk + 2) * 1024 * 256;  // raw z rows for step k
  const int l15 = lane & 15, quad = lane >> 4;

  const int c0 = (wv == 0) ? 0 : (4 * wv + 1);
  const int nc = (wv == 0) ? 5 : 4;
  // chain row indices: depend only on l15, so every lane holds its own row
  // directly (no shfl needed). Lanes with equal l15 across quads agree.
  int iv[5];
#pragma unroll
  for (int j = 0; j < 5; ++j) {
    if (j < nc) {
      const int c = c0 + j;
      if (c == 0) iv[j] = m0 + l15;
      else {
        int idx = ridx[(m0 + (c - 1)) * NEG_ + l15];
        iv[j] = idx < 0 ? 0 : (idx >= Mk ? Mk - 1 : idx);
      }
    } else iv[j] = 0;
  }

  // ---- issue ALL fragment loads upfront (af + b0..b4), then pin ----
  // B-frag lane(l15,quad): Z[iv[j]][quad*8 + tv*32 .. +8] — identical values
  // to the old LDS-staged transpose.
  bf16x8 af[8];
  {
    const unsigned short* p = Yc + (size_t)(m0 + l15) * 256 + quad * 8;
#pragma unroll
    for (int tv = 0; tv < 8; ++tv) af[tv] = *(const bf16x8*)(p + tv * 32);
  }
  bf16x8 b0[8], b1[8], b2[8], b3[8], b4[8];
  {
    const unsigned short* p0 = Z + (size_t)iv[0] * 256 + quad * 8;
    const unsigned short* p1 = Z + (size_t)iv[1] * 256 + quad * 8;
    const unsigned short* p2 = Z + (size_t)iv[2] * 256 + quad * 8;
    const unsigned short* p3 = Z + (size_t)iv[3] * 256 + quad * 8;
#pragma unroll
    for (int tv = 0; tv < 8; ++tv) b0[tv] = *(const bf16x8*)(p0 + tv * 32);
#pragma unroll
    for (int tv = 0; tv < 8; ++tv) b1[tv] = *(const bf16x8*)(p1 + tv * 32);
#pragma unroll
    for (int tv = 0; tv < 8; ++tv) b2[tv] = *(const bf16x8*)(p2 + tv * 32);
#pragma unroll
    for (int tv = 0; tv < 8; ++tv) b3[tv] = *(const bf16x8*)(p3 + tv * 32);
    if (nc == 5) {
      const unsigned short* p4 = Z + (size_t)iv[4] * 256 + quad * 8;
#pragma unroll
      for (int tv = 0; tv < 8; ++tv) b4[tv] = *(const bf16x8*)(p4 + tv * 32);
    }
  }
  // Pin: nothing (esp. the loads above) may be scheduled across this point.
  __builtin_amdgcn_sched_barrier(0);

  // ---- MFMA clusters; compiler emits counted vmcnt per buffer ----
  auto emit = [&](int j, const f32x4& acc) {
    const int c = c0 + j;
    if (c == 0) {
#pragma unroll
      for (int r = 0; r < 4; ++r)
        if (l15 == quad * 4 + r) L[(quad * 4 + r) * LDW] = acc[r];
    } else {
      const int i = c - 1;
      if (quad == (i >> 2)) L[i * LDW + 1 + l15] = acc[i & 3];
    }
  };
  {
    f32x4 acc = {};
#pragma unroll
    for (int tv = 0; tv < 8; ++tv)
      acc = __builtin_amdgcn_mfma_f32_16x16x32_bf16(af[tv], b0[tv], acc, 0, 0, 0);
    emit(0, acc);
  }
  {
    f32x4 acc = {};
#pragma unroll
    for (int tv = 0; tv < 8; ++tv)
      acc = __builtin_amdgcn_mfma_f32_16x16x32_bf16(af[tv], b1[tv], acc, 0, 0, 0);
    emit(1, acc);
  }
  {
    f32x4 acc = {};
#pragma unroll
    for (int tv = 0; tv < 8; ++tv)
      acc = __builtin_amdgcn_mfma_f32_16x16x32_bf16(af[tv], b2[tv], acc, 0, 0, 0);
    emit(2, acc);
  }
  {
    f32x4 acc = {};
#pragma unroll
    for (int tv = 0; tv < 8; ++tv)
      acc = __builtin_amdgcn_mfma_f32_16x16x32_bf16(af[tv], b3[tv], acc, 0, 0, 0);
    emit(3, acc);
  }
  if (nc == 5) {
    f32x4 acc = {};
#pragma unroll
    for (int tv = 0; tv < 8; ++tv)
      acc = __builtin_amdgcn_mfma_f32_16x16x32_bf16(af[tv], b4[tv], acc, 0, 0, 0);
    emit(4, acc);
  }
  __syncthreads();
  if (threadIdx.x < 16) {
    float mainv = L[threadIdx.x * LDW];
    float mx = mainv;
    float nv[NEG_];
#pragma unroll
    for (int n = 0; n < NEG_; ++n) {
      nv[n] = L[threadIdx.x * LDW + 1 + n];
      mx = fmaxf(mx, nv[n]);
    }
    float num = __expf(mainv - mx);
    float se = num;
#pragma unroll
    for (int n = 0; n < NEG_; ++n) se += __expf(nv[n] - mx);
    Lk[kk * 14336 + m0 + threadIdx.x] = -logf(num / se + EPS_);
  }
}

// ---- patchwise loss + counts (blocks 0..63); total loss (blocks 64..123) ----
__global__ __launch_bounds__(256) void finalize_pl(
    const float* __restrict__ Lk, float* __restrict__ out) {
  if (blockIdx.x < 64) {
    int idx = blockIdx.x * 256 + threadIdx.x;   // b*256 + h*16 + w
    int b = idx >> 8, h = (idx >> 4) & 15, w = idx & 15;
    float v = 0.f;
#pragma unroll
    for (int kk = 0; kk < PRED_; ++kk) {
      int off = kk + 2;
      if (h >= off)      v += Lk[kk * 14336 + ((h - off) * 16 + w) * 64 + b];
      if (h <= 15 - off) v += Lk[kk * 14336 + (h * 16 + w) * 64 + b];
    }
    out[1 + idx] = v;
    if (idx < 256) {
      int hh = idx >> 4;
      float cnt = 0.f;
#pragma unroll
      for (int off = 2; off <= 6; ++off)
        cnt += (hh >= off ? 1.f : 0.f) + (hh <= 15 - off ? 1.f : 0.f);
      out[1 + 16384 + idx] = cnt;
    }
  } else {
    // total loss: 60 blocks x 1024 elements, float4 loads, atomicAdd.
    __shared__ float red[4];
    const int cb = blockIdx.x - 64;             // 0..59
    const int kk = cb < 14 ? 0 : cb < 27 ? 1 : cb < 39 ? 2 : cb < 50 ? 3 : 4;
    const int s0 = kk == 0 ? 0 : kk == 1 ? 14 : kk == 2 ? 27 : kk == 3 ? 39 : 50;
    const float scale = 1.0f / (5120.0f * (float)(14 - kk));
    const int e = (cb - s0) * 1024 + threadIdx.x * 4;
    float4 v = *(const float4*)&Lk[kk * 14336 + e];
    float local = (v.x + v.y + v.z + v.w) * scale;
#pragma unroll
    for (int s = 32; s; s >>= 1) local += __shfl_down(local, s);
    if ((threadIdx.x & 63) == 0) red[threadIdx.x >> 6] = local;
    __syncthreads();
    if (threadIdx.x == 0)
      atomicAdd(out, red[0] + red[1] + red[2] + red[3]);
  }
}

extern "C" void kernel_launch(void* const* d_in, const int* in_sizes, int n_in,
                              void* d_out, int out_size, void* d_ws, size_t ws_size,
                              hipStream_t stream) {
  const float* z  = (const float*)d_in[0];
  const float* c  = (const float*)d_in[1];
  const float* Wk = (const float*)d_in[2];
  float* out = (float*)d_out;
  char* wsb = (char*)d_ws;
  unsigned short* Zp = (unsigned short*)(wsb);
  unsigned short* Cb = (unsigned short*)(wsb + 8388608);
  unsigned short* Wb = (unsigned short*)(wsb + 16777216);
  unsigned short* Cw = (unsigned short*)(wsb + 17432576);
  float*          Lk = (float*)(wsb + 54132736);

  prep_all<<<dim3(256, 8, 2), 256, 0, stream>>>(z, c, Wk, Zp, Cb, Wb, out);
  gemm_all<<<dim3(2, 112, PRED_), 256, 0, stream>>>(Cb, Wb, Cw);
  score_all<<<3840, 256, 0, stream>>>(
      Cw, Zp, (const int*)d_in[3], (const int*)d_in[4], (const int*)d_in[5],
      (const int*)d_in[6], (const int*)d_in[7], Lk);
  finalize_pl<<<124, 256, 0, stream>>>(Lk, out);
}

// Round 6
// 180.945 us; speedup vs baseline: 1.0278x; 1.0278x over previous
//
#include <hip/hip_runtime.h>
#include <hip/hip_bf16.h>
#include <math.h>

#define NEG_ 16
#define PRED_ 5
#define EPS_ 1e-11f
#define LDW 18    // logit tile row stride (floats)
#define GSTR 272  // score LDS gather-row stride in shorts (544 B)
#define ASTR 72   // gemm LDS tile row stride in shorts (144 B, odd16 -> conflict-free b128)
#define SPLIT_ROW 8192   // global Zp row split: pass A < 8192 <= pass B
#define NEGINF_ -1e30f

typedef __attribute__((ext_vector_type(8))) short bf16x8;
typedef __attribute__((ext_vector_type(4))) float f32x4;

static __device__ __forceinline__ unsigned short f2bu(float f) {
  __hip_bfloat16 h = __float2bfloat16(f);
  return *(unsigned short*)&h;
}

// ws layout (bytes):
//   statsA f32 [5][14336][3] : 0      (inside Zp dead head: Zp rows<2048 never used)
//   Zp bf16 [16384][256] : 0         rows = (h*16+w)*64+b; rows<2048 NEVER touched
//   Cb bf16 [16384][256] : 8388608   rows>=14336 never touched
//   Wb bf16 [5][256][256]: 16777216  TRANSPOSED: Wb[k][o][i] = Wk[k][i][o]
//   Cw bf16 [5][14336][256]: 17432576  projected CONTEXT (Wk^T ctx)
//   Lk f32  [5][14336]   : 54132736
// Purity: every read is of data written earlier in this launch.
// out[0] is re-zeroed by prep_all each launch (finalize atomicAdds into it).
//
// score is SPLIT into two range-passes so the random negative gathers hit an
// L2-resident slice of Zp (pass A: rows [2048,8192) = 3 MB; pass B: rows
// [8192,16384) = 4 MB; per-XCD L2 = 4 MB). Out-of-pass lanes gather a dummy
// in-range row and their logit slots get -1e30. Pass A stores per-row partial
// softmax stats (max, sumexp, mainv); pass B merges -> identical math.

// ---- prep: transpose z/c (+cast) with 128B-coalesced reads AND writes ----
__global__ __launch_bounds__(256) void prep_all(
    const float* __restrict__ z, const float* __restrict__ c,
    const float* __restrict__ Wk,
    unsigned short* __restrict__ Zp, unsigned short* __restrict__ Cb,
    unsigned short* __restrict__ Wb, float* __restrict__ out) {
  __shared__ float tile[32][65];   // [q][p]
  const int t = threadIdx.x;
  if (blockIdx.x == 0 && blockIdx.y == 0 && blockIdx.z == 0 && t == 0)
    out[0] = 0.f;   // total-loss accumulator, replay-safe zeroing
  if (blockIdx.y == 7) {
    // Wk TRANSPOSE (+cast): 5 matrices of 256x256, 32x32 LDS tiles.
    int ib = blockIdx.z * 256 + blockIdx.x;   // 0..511; need 320 = 5 k * 64 tiles
    if (ib < 320) {
      const int k = ib >> 6, tl = ib & 63;
      const int r0 = (tl >> 3) * 32, c0g = (tl & 7) * 32;
      const int tx = t & 31, ty = t >> 5;     // (32,8)
#pragma unroll
      for (int r = 0; r < 32; r += 8)
        tile[ty + r][tx] = Wk[k * 65536 + (r0 + ty + r) * 256 + c0g + tx];
      __syncthreads();
#pragma unroll
      for (int r = 0; r < 32; r += 8)   // Wb[k][o][i] = Wk[k][i][o]
        Wb[k * 65536 + (c0g + ty + r) * 256 + r0 + tx] = f2bu(tile[tx][ty + r]);
    }
    return;
  }
  const float* in = blockIdx.z ? c : z;
  unsigned short* out2 = blockIdx.z ? Cb : Zp;
  const int p0 = blockIdx.x * 64;                          // [0,16384)
  const int q0 = blockIdx.y * 32 + (blockIdx.z ? 0 : 32);  // z:[32,256) c:[0,224)
  const int tx = t & 31, ty = t >> 5;       // (32,8)
#pragma unroll
  for (int r = 0; r < 64; r += 8)
    tile[tx][ty + r] = in[(size_t)(p0 + ty + r) * 256 + q0 + tx];
  __syncthreads();
  const int pp = t & 63, wq = t >> 6;       // (64,4)
#pragma unroll
  for (int r = 0; r < 32; r += 4)
    out2[(size_t)(q0 + wq + r) * 16384 + p0 + pp] = f2bu(tile[wq + r][pp]);
}

// ---- LDS-staged MFMA GEMM: 128x128 tile, BK=64 ----
// Computes Cw_k[m][o] = sum_i Cb[m][i] * Wb_k[o][i] = (Wk^T ctx[m])[o].
__global__ __launch_bounds__(256) void gemm_all(
    const unsigned short* __restrict__ Cb, const unsigned short* __restrict__ Wb,
    unsigned short* __restrict__ Cw) {
  const int kk = blockIdx.z;
  const int Mk = (14 - kk) * 1024;
  const int m0b = blockIdx.y * 128;
  if (m0b >= Mk) return;
  const unsigned short* A = Cb;
  const unsigned short* Wm = Wb + (size_t)kk * 65536;
  unsigned short* Y = Cw + (size_t)kk * 14336 * 256;
  __shared__ unsigned short As[128 * ASTR];
  __shared__ unsigned short Bs[128 * ASTR];
  const int t = threadIdx.x;
  const int wid = t >> 6, lane = t & 63;
  const int wm = wid >> 1, wn = wid & 1;
  const int l15 = lane & 15, quad = lane >> 4;
  const int n0 = blockIdx.x * 128;
  const int srow = t >> 1, shalf = t & 1;
  const unsigned short* ga = A + (size_t)(m0b + srow) * 256 + shalf * 32;
  const unsigned short* gb = Wm + (size_t)(n0 + srow) * 256 + shalf * 32;
  unsigned short* wa = As + srow * ASTR + shalf * 32;
  unsigned short* wb = Bs + srow * ASTR + shalf * 32;
  f32x4 acc[4][4] = {};
  bf16x8 ra[4], rb[4];
#pragma unroll
  for (int cs = 0; cs < 4; ++cs) {
    ra[cs] = *(const bf16x8*)(ga + cs * 8);
    rb[cs] = *(const bf16x8*)(gb + cs * 8);
  }
#pragma unroll
  for (int ki = 0; ki < 4; ++ki) {
    __syncthreads();
#pragma unroll
    for (int cs = 0; cs < 4; ++cs) {
      *(bf16x8*)(wa + cs * 8) = ra[cs];
      *(bf16x8*)(wb + cs * 8) = rb[cs];
    }
    __syncthreads();
    if (ki < 3) {
      const int k1 = (ki + 1) * 64;
#pragma unroll
      for (int cs = 0; cs < 4; ++cs) {
        ra[cs] = *(const bf16x8*)(ga + k1 + cs * 8);
        rb[cs] = *(const bf16x8*)(gb + k1 + cs * 8);
      }
    }
#pragma unroll
    for (int ks = 0; ks < 2; ++ks) {
      bf16x8 af[4], bf[4];
#pragma unroll
      for (int tm = 0; tm < 4; ++tm)
        af[tm] = *(const bf16x8*)(As + (wm * 64 + tm * 16 + l15) * ASTR + ks * 32 + quad * 8);
#pragma unroll
      for (int tn = 0; tn < 4; ++tn)
        bf[tn] = *(const bf16x8*)(Bs + (wn * 64 + tn * 16 + l15) * ASTR + ks * 32 + quad * 8);
#pragma unroll
      for (int tm = 0; tm < 4; ++tm)
#pragma unroll
        for (int tn = 0; tn < 4; ++tn)
          acc[tm][tn] = __builtin_amdgcn_mfma_f32_16x16x32_bf16(
              af[tm], bf[tn], acc[tm][tn], 0, 0, 0);
    }
  }
#pragma unroll
  for (int tm = 0; tm < 4; ++tm)
#pragma unroll
    for (int tn = 0; tn < 4; ++tn)
#pragma unroll
      for (int r = 0; r < 4; ++r)
        Y[(size_t)(m0b + wm * 64 + tm * 16 + quad * 4 + r) * 256 +
          n0 + wn * 64 + tn * 16 + l15] = f2bu(acc[tm][tn][r]);
}

// ---- fused scoring, range-split pass (PASS 0: rows<8192; PASS 1: >=8192) ----
template <int PASS>
__global__ __launch_bounds__(256) void score_pass(
    const unsigned short* __restrict__ Cw, const unsigned short* __restrict__ Zp,
    const int* __restrict__ r1, const int* __restrict__ r2,
    const int* __restrict__ r3, const int* __restrict__ r4,
    const int* __restrict__ r5, float* __restrict__ statsA,
    float* __restrict__ Lk) {
  __shared__ __align__(16) unsigned short gbuf[4][16 * GSTR];
  __shared__ float L[16 * LDW];
  const int wv = threadIdx.x >> 6, lane = threadIdx.x & 63;
  const int gid = blockIdx.x;
  int kk, base;
  if (gid < 896)       { kk = 0; base = 0; }
  else if (gid < 1728) { kk = 1; base = 896; }
  else if (gid < 2496) { kk = 2; base = 1728; }
  else if (gid < 3200) { kk = 3; base = 2496; }
  else                 { kk = 4; base = 3200; }
  const int Mk = (14 - kk) * 1024;
  const int m0 = (gid - base) * 16;
  const int base_off = (kk + 2) * 1024;        // Z-relative -> global Zp row
  const int* ridx = kk == 0 ? r1 : kk == 1 ? r2 : kk == 2 ? r3 : kk == 3 ? r4 : r5;
  const unsigned short* Yc = Cw + (size_t)kk * 14336 * 256;       // projected ctx
  const unsigned short* Z  = Zp + (size_t)base_off * 256;          // raw z rows
  const int l15 = lane & 15, quad = lane >> 4;
  const int half = lane >> 5, ch = lane & 31;
  unsigned short* mybuf = gbuf[wv];

  auto gather = [&](const unsigned short* src, int ivv, bf16x8* dst) {
#pragma unroll
    for (int j = 0; j < 8; ++j) {
      int rlo = __shfl(ivv, 2 * j);
      int rhi = __shfl(ivv, 2 * j + 1);
      int row = half ? rhi : rlo;
      dst[j] = *(const bf16x8*)(src + (size_t)row * 256 + ch * 8);
    }
  };
  auto stage = [&](const bf16x8* g) {
#pragma unroll
    for (int j2 = 0; j2 < 8; ++j2)
      *(bf16x8*)(mybuf + (2 * j2 + half) * GSTR + ch * 8) = g[j2];
  };

  const int c0 = (wv == 0) ? 0 : (4 * wv + 1);
  const int nc = (wv == 0) ? 5 : 4;
  // Per-lane entry rows + pass predicates. ivp = row to gather THIS pass
  // (dummy in-pass row for entries owned by the other pass).
  int ivp[5];
  bool pe[5];
  const int dummyB = SPLIT_ROW - base_off;     // global row 8192, in pass-B range
#pragma unroll
  for (int j = 0; j < 5; ++j) {
    ivp[j] = 0; pe[j] = false;
    if (j < nc) {
      const int c = c0 + j;
      int rel;
      if (c == 0) rel = m0 + l15;
      else {
        int idx = ridx[(m0 + (c - 1)) * NEG_ + l15];
        rel = idx < 0 ? 0 : (idx >= Mk ? Mk - 1 : idx);
      }
      const bool inA = (rel + base_off) < SPLIT_ROW;
      pe[j] = (PASS == 0) ? inA : !inA;
      ivp[j] = pe[j] ? rel : (PASS == 0 ? 0 : dummyB);
    }
  }

  // A-fragment: rows m0..m0+15 of projected ctx. Non-temporal: this is a
  // 31 MB stream that must not evict the L2-resident Zp slice.
  bf16x8 af[8];
  {
    bf16x8 g[8];
#pragma unroll
    for (int j = 0; j < 8; ++j) {
      int row = m0 + (half ? 2 * j + 1 : 2 * j) - 0;
      // rows are m0 + (2j+half) via the same half-split as gather
      g[j] = __builtin_nontemporal_load(
          (const bf16x8*)(Yc + (size_t)(m0 + 2 * j + half) * 256 + ch * 8));
      (void)row;
    }
    stage(g);
#pragma unroll
    for (int tv = 0; tv < 8; ++tv)
      af[tv] = *(const bf16x8*)(mybuf + l15 * GSTR + quad * 8 + tv * 32);
  }

  bf16x8 bA[8], bB[8];
  gather(Z, ivp[0], bA);
  if (nc > 1) gather(Z, ivp[1], bB);

#pragma unroll
  for (int j = 0; j < 5; ++j) {
    if (j < nc) {
      if (j & 1) {
        stage(bB);
        if (j + 2 < nc) gather(Z, ivp[j + 2], bB);
      } else {
        stage(bA);
        if (j + 2 < nc) gather(Z, ivp[j + 2], bA);
      }
      f32x4 acc = {};
#pragma unroll
      for (int tv = 0; tv < 8; ++tv) {
        bf16x8 bfv = *(const bf16x8*)(mybuf + l15 * GSTR + quad * 8 + tv * 32);
        acc = __builtin_amdgcn_mfma_f32_16x16x32_bf16(af[tv], bfv, acc, 0, 0, 0);
      }
      const int c = c0 + j;
      if (c == 0) {
#pragma unroll
        for (int r = 0; r < 4; ++r)
          if (l15 == quad * 4 + r) L[(quad * 4 + r) * LDW] = pe[j] ? acc[r] : NEGINF_;
      } else {
        const int i = c - 1;
        if (quad == (i >> 2)) L[i * LDW + 1 + l15] = pe[j] ? acc[i & 3] : NEGINF_;
      }
    }
  }
  __syncthreads();
  if (threadIdx.x < 16) {
    const int t = threadIdx.x;
    float mainv = L[t * LDW];
    float mx = mainv;
    float nv[NEG_];
#pragma unroll
    for (int n = 0; n < NEG_; ++n) {
      nv[n] = L[t * LDW + 1 + n];
      mx = fmaxf(mx, nv[n]);
    }
    float s;
    if (mx < -1e29f) {
      s = 0.f;   // nothing in this pass for this row
    } else {
      s = __expf(mainv - mx);   // excluded entries: exp(-1e30 - mx) -> 0
#pragma unroll
      for (int n = 0; n < NEG_; ++n) s += __expf(nv[n] - mx);
    }
    const int rowi = kk * 14336 + m0 + t;
    if (PASS == 0) {
      statsA[rowi * 3 + 0] = mx;
      statsA[rowi * 3 + 1] = s;
      statsA[rowi * 3 + 2] = mainv;
    } else {
      const float mA = statsA[rowi * 3 + 0];
      const float sA = statsA[rowi * 3 + 1];
      const float mvA = statsA[rowi * 3 + 2];
      const bool mainB = (m0 + t + base_off) >= SPLIT_ROW;
      const float mv = mainB ? mainv : mvA;
      const float m = fmaxf(mA, mx);
      const float se = sA * __expf(mA - m) + s * __expf(mx - m);
      Lk[rowi] = -logf(__expf(mv - m) / se + EPS_);
    }
  }
}

// ---- patchwise loss + counts (blocks 0..63); total loss (blocks 64..123) ----
__global__ __launch_bounds__(256) void finalize_pl(
    const float* __restrict__ Lk, float* __restrict__ out) {
  if (blockIdx.x < 64) {
    int idx = blockIdx.x * 256 + threadIdx.x;   // b*256 + h*16 + w
    int b = idx >> 8, h = (idx >> 4) & 15, w = idx & 15;
    float v = 0.f;
#pragma unroll
    for (int kk = 0; kk < PRED_; ++kk) {
      int off = kk + 2;
      if (h >= off)      v += Lk[kk * 14336 + ((h - off) * 16 + w) * 64 + b];
      if (h <= 15 - off) v += Lk[kk * 14336 + (h * 16 + w) * 64 + b];
    }
    out[1 + idx] = v;
    if (idx < 256) {
      int hh = idx >> 4;
      float cnt = 0.f;
#pragma unroll
      for (int off = 2; off <= 6; ++off)
        cnt += (hh >= off ? 1.f : 0.f) + (hh <= 15 - off ? 1.f : 0.f);
      out[1 + 16384 + idx] = cnt;
    }
  } else {
    // total loss: 60 blocks x 1024 elements, float4 loads, atomicAdd.
    __shared__ float red[4];
    const int cb = blockIdx.x - 64;             // 0..59
    const int kk = cb < 14 ? 0 : cb < 27 ? 1 : cb < 39 ? 2 : cb < 50 ? 3 : 4;
    const int s0 = kk == 0 ? 0 : kk == 1 ? 14 : kk == 2 ? 27 : kk == 3 ? 39 : 50;
    const float scale = 1.0f / (5120.0f * (float)(14 - kk));
    const int e = (cb - s0) * 1024 + threadIdx.x * 4;
    float4 v = *(const float4*)&Lk[kk * 14336 + e];
    float local = (v.x + v.y + v.z + v.w) * scale;
#pragma unroll
    for (int s = 32; s; s >>= 1) local += __shfl_down(local, s);
    if ((threadIdx.x & 63) == 0) red[threadIdx.x >> 6] = local;
    __syncthreads();
    if (threadIdx.x == 0)
      atomicAdd(out, red[0] + red[1] + red[2] + red[3]);
  }
}

extern "C" void kernel_launch(void* const* d_in, const int* in_sizes, int n_in,
                              void* d_out, int out_size, void* d_ws, size_t ws_size,
                              hipStream_t stream) {
  const float* z  = (const float*)d_in[0];
  const float* c  = (const float*)d_in[1];
  const float* Wk = (const float*)d_in[2];
  float* out = (float*)d_out;
  char* wsb = (char*)d_ws;
  float*          SA = (float*)(wsb);            // statsA in Zp dead head (<1 MB)
  unsigned short* Zp = (unsigned short*)(wsb);
  unsigned short* Cb = (unsigned short*)(wsb + 8388608);
  unsigned short* Wb = (unsigned short*)(wsb + 16777216);
  unsigned short* Cw = (unsigned short*)(wsb + 17432576);
  float*          Lk = (float*)(wsb + 54132736);

  prep_all<<<dim3(256, 8, 2), 256, 0, stream>>>(z, c, Wk, Zp, Cb, Wb, out);
  gemm_all<<<dim3(2, 112, PRED_), 256, 0, stream>>>(Cb, Wb, Cw);
  score_pass<0><<<3840, 256, 0, stream>>>(
      Cw, Zp, (const int*)d_in[3], (const int*)d_in[4], (const int*)d_in[5],
      (const int*)d_in[6], (const int*)d_in[7], SA, Lk);
  score_pass<1><<<3840, 256, 0, stream>>>(
      Cw, Zp, (const int*)d_in[3], (const int*)d_in[4], (const int*)d_in[5],
      (const int*)d_in[6], (const int*)d_in[7], SA, Lk);
  finalize_pl<<<124, 256, 0, stream>>>(Lk, out);
}

// Round 8
// 157.409 us; speedup vs baseline: 1.1815x; 1.1495x over previous
//
#include <hip/hip_runtime.h>
#include <hip/hip_bf16.h>
#include <math.h>

#define NEG_ 16
#define PRED_ 5
#define EPS_ 1e-11f
#define LDW 18    // logit tile row stride (floats)
#define GSTR 272  // score LDS gather-row stride in shorts (544 B)
#define ASTR 72   // gemm LDS tile row stride in shorts (144 B, odd16 -> conflict-free b128)

typedef __attribute__((ext_vector_type(8))) short bf16x8;
typedef __attribute__((ext_vector_type(4))) float f32x4;

static __device__ __forceinline__ unsigned short f2bu(float f) {
  __hip_bfloat16 h = __float2bfloat16(f);
  return *(unsigned short*)&h;
}

// ws layout (bytes):
//   Zp bf16 [16384][256] : 0         rows = (h*16+w)*64+b; rows<2048 never touched
//   Cb bf16 [16384][256] : 8388608   rows>=14336 never touched
//   Wb bf16 [5][256][256]: 16777216  TRANSPOSED: Wb[k][o][i] = Wk[k][i][o]
//   Cw bf16 [5][14336][256]: 17432576  projected CONTEXT (Wk^T ctx)
//   Lk f32  [5][14336]   : 54132736  tails [Mk,14336) NEVER read -> no memset
// Purity: every read is of data written earlier in this launch.
// out[0] is re-zeroed by prep_all each launch (finalize atomicAdds into it).
//
// R6 lesson: score time tracks GATHER REQUEST COUNT, not data location
// (L2-split halved HBM traffic, time unchanged). Bottleneck = resident-wave
// concurrency: 3.5us blocks can't sustain the 4-block/CU LDS cap. Fix here:
// PERSISTENT blocks — grid=1024 (exactly 4/CU), each grid-strides over the
// 3840 tiles, so all blocks stay resident the whole kernel.
// (R7 was an infra failure; this is the same candidate resubmitted.)

// ---- prep: transpose z/c (+cast) with 128B-coalesced reads AND writes ----
__global__ __launch_bounds__(256) void prep_all(
    const float* __restrict__ z, const float* __restrict__ c,
    const float* __restrict__ Wk,
    unsigned short* __restrict__ Zp, unsigned short* __restrict__ Cb,
    unsigned short* __restrict__ Wb, float* __restrict__ out) {
  __shared__ float tile[32][65];   // [q][p]
  const int t = threadIdx.x;
  if (blockIdx.x == 0 && blockIdx.y == 0 && blockIdx.z == 0 && t == 0)
    out[0] = 0.f;   // total-loss accumulator, replay-safe zeroing
  if (blockIdx.y == 7) {
    // Wk TRANSPOSE (+cast): 5 matrices of 256x256, 32x32 LDS tiles.
    int ib = blockIdx.z * 256 + blockIdx.x;   // 0..511; need 320 = 5 k * 64 tiles
    if (ib < 320) {
      const int k = ib >> 6, tl = ib & 63;
      const int r0 = (tl >> 3) * 32, c0g = (tl & 7) * 32;
      const int tx = t & 31, ty = t >> 5;     // (32,8)
#pragma unroll
      for (int r = 0; r < 32; r += 8)
        tile[ty + r][tx] = Wk[k * 65536 + (r0 + ty + r) * 256 + c0g + tx];
      __syncthreads();
#pragma unroll
      for (int r = 0; r < 32; r += 8)   // Wb[k][o][i] = Wk[k][i][o]
        Wb[k * 65536 + (c0g + ty + r) * 256 + r0 + tx] = f2bu(tile[tx][ty + r]);
    }
    return;
  }
  const float* in = blockIdx.z ? c : z;
  unsigned short* out2 = blockIdx.z ? Cb : Zp;
  const int p0 = blockIdx.x * 64;                          // [0,16384)
  const int q0 = blockIdx.y * 32 + (blockIdx.z ? 0 : 32);  // z:[32,256) c:[0,224)
  const int tx = t & 31, ty = t >> 5;       // (32,8)
#pragma unroll
  for (int r = 0; r < 64; r += 8)
    tile[tx][ty + r] = in[(size_t)(p0 + ty + r) * 256 + q0 + tx];
  __syncthreads();
  const int pp = t & 63, wq = t >> 6;       // (64,4)
#pragma unroll
  for (int r = 0; r < 32; r += 4)
    out2[(size_t)(q0 + wq + r) * 16384 + p0 + pp] = f2bu(tile[wq + r][pp]);
}

// ---- LDS-staged MFMA GEMM: 128x128 tile, BK=64 ----
// Computes Cw_k[m][o] = sum_i Cb[m][i] * Wb_k[o][i] = (Wk^T ctx[m])[o].
__global__ __launch_bounds__(256) void gemm_all(
    const unsigned short* __restrict__ Cb, const unsigned short* __restrict__ Wb,
    unsigned short* __restrict__ Cw) {
  const int kk = blockIdx.z;
  const int Mk = (14 - kk) * 1024;
  const int m0b = blockIdx.y * 128;
  if (m0b >= Mk) return;
  const unsigned short* A = Cb;
  const unsigned short* Wm = Wb + (size_t)kk * 65536;
  unsigned short* Y = Cw + (size_t)kk * 14336 * 256;
  __shared__ unsigned short As[128 * ASTR];
  __shared__ unsigned short Bs[128 * ASTR];
  const int t = threadIdx.x;
  const int wid = t >> 6, lane = t & 63;
  const int wm = wid >> 1, wn = wid & 1;
  const int l15 = lane & 15, quad = lane >> 4;
  const int n0 = blockIdx.x * 128;
  const int srow = t >> 1, shalf = t & 1;
  const unsigned short* ga = A + (size_t)(m0b + srow) * 256 + shalf * 32;
  const unsigned short* gb = Wm + (size_t)(n0 + srow) * 256 + shalf * 32;
  unsigned short* wa = As + srow * ASTR + shalf * 32;
  unsigned short* wb = Bs + srow * ASTR + shalf * 32;
  f32x4 acc[4][4] = {};
  bf16x8 ra[4], rb[4];
#pragma unroll
  for (int cs = 0; cs < 4; ++cs) {
    ra[cs] = *(const bf16x8*)(ga + cs * 8);
    rb[cs] = *(const bf16x8*)(gb + cs * 8);
  }
#pragma unroll
  for (int ki = 0; ki < 4; ++ki) {
    __syncthreads();
#pragma unroll
    for (int cs = 0; cs < 4; ++cs) {
      *(bf16x8*)(wa + cs * 8) = ra[cs];
      *(bf16x8*)(wb + cs * 8) = rb[cs];
    }
    __syncthreads();
    if (ki < 3) {
      const int k1 = (ki + 1) * 64;
#pragma unroll
      for (int cs = 0; cs < 4; ++cs) {
        ra[cs] = *(const bf16x8*)(ga + k1 + cs * 8);
        rb[cs] = *(const bf16x8*)(gb + k1 + cs * 8);
      }
    }
#pragma unroll
    for (int ks = 0; ks < 2; ++ks) {
      bf16x8 af[4], bf[4];
#pragma unroll
      for (int tm = 0; tm < 4; ++tm)
        af[tm] = *(const bf16x8*)(As + (wm * 64 + tm * 16 + l15) * ASTR + ks * 32 + quad * 8);
#pragma unroll
      for (int tn = 0; tn < 4; ++tn)
        bf[tn] = *(const bf16x8*)(Bs + (wn * 64 + tn * 16 + l15) * ASTR + ks * 32 + quad * 8);
#pragma unroll
      for (int tm = 0; tm < 4; ++tm)
#pragma unroll
        for (int tn = 0; tn < 4; ++tn)
          acc[tm][tn] = __builtin_amdgcn_mfma_f32_16x16x32_bf16(
              af[tm], bf[tn], acc[tm][tn], 0, 0, 0);
    }
  }
#pragma unroll
  for (int tm = 0; tm < 4; ++tm)
#pragma unroll
    for (int tn = 0; tn < 4; ++tn)
#pragma unroll
      for (int r = 0; r < 4; ++r)
        Y[(size_t)(m0b + wm * 64 + tm * 16 + quad * 4 + r) * 256 +
          n0 + wn * 64 + tn * 16 + l15] = f2bu(acc[tm][tn][r]);
}

// ---- fused scoring: persistent blocks, grid-stride over 3840 tiles ----
__global__ __launch_bounds__(256) void score_all(
    const unsigned short* __restrict__ Cw, const unsigned short* __restrict__ Zp,
    const int* __restrict__ r1, const int* __restrict__ r2,
    const int* __restrict__ r3, const int* __restrict__ r4,
    const int* __restrict__ r5, float* __restrict__ Lk) {
  __shared__ __align__(16) unsigned short gbuf[4][16 * GSTR];
  __shared__ float L[16 * LDW];
  const int wv = threadIdx.x >> 6, lane = threadIdx.x & 63;
  const int l15 = lane & 15, quad = lane >> 4;
  const int half = lane >> 5, ch = lane & 31;
  unsigned short* mybuf = gbuf[wv];

  auto stage = [&](const bf16x8* g) {
#pragma unroll
    for (int j2 = 0; j2 < 8; ++j2)
      *(bf16x8*)(mybuf + (2 * j2 + half) * GSTR + ch * 8) = g[j2];
  };

  const int c0 = (wv == 0) ? 0 : (4 * wv + 1);
  const int nc = (wv == 0) ? 5 : 4;

  for (int gid = blockIdx.x; gid < 3840; gid += gridDim.x) {
    int kk, base;
    if (gid < 896)       { kk = 0; base = 0; }
    else if (gid < 1728) { kk = 1; base = 896; }
    else if (gid < 2496) { kk = 2; base = 1728; }
    else if (gid < 3200) { kk = 3; base = 2496; }
    else                 { kk = 4; base = 3200; }
    const int Mk = (14 - kk) * 1024;
    const int m0 = (gid - base) * 16;
    const int* ridx = kk == 0 ? r1 : kk == 1 ? r2 : kk == 2 ? r3 : kk == 3 ? r4 : r5;
    const unsigned short* Yc = Cw + (size_t)kk * 14336 * 256;       // projected ctx
    const unsigned short* Z  = Zp + (size_t)(kk + 2) * 1024 * 256;  // raw z rows

    auto gather = [&](const unsigned short* src, int ivv, bf16x8* dst) {
#pragma unroll
      for (int j = 0; j < 8; ++j) {
        int rlo = __shfl(ivv, 2 * j);
        int rhi = __shfl(ivv, 2 * j + 1);
        int row = half ? rhi : rlo;
        dst[j] = *(const bf16x8*)(src + (size_t)row * 256 + ch * 8);
      }
    };

    // chain indices upfront: ridx dword loads issue in parallel.
    int iv[5];
#pragma unroll
    for (int j = 0; j < 5; ++j) {
      if (j < nc) {
        const int c = c0 + j;
        if (c == 0) iv[j] = m0 + l15;
        else {
          int idx = ridx[(m0 + (c - 1)) * NEG_ + l15];
          iv[j] = idx < 0 ? 0 : (idx >= Mk ? Mk - 1 : idx);
        }
      } else iv[j] = 0;
    }

    bf16x8 af[8];
    {
      bf16x8 g[8];
      gather(Yc, m0 + l15, g);   // contiguous rows of projected context
      stage(g);
#pragma unroll
      for (int tv = 0; tv < 8; ++tv)
        af[tv] = *(const bf16x8*)(mybuf + l15 * GSTR + quad * 8 + tv * 32);
    }

    // depth-1 pipeline: gather(j+1) in flight while staging/MFMA chain j.
    bf16x8 g[8], gn[8];
    gather(Z, iv[0], g);
    for (int j = 0; j < nc; ++j) {
      if (j + 1 < nc) gather(Z, iv[j + 1], gn);
      stage(g);
      f32x4 acc = {};
#pragma unroll
      for (int tv = 0; tv < 8; ++tv) {
        bf16x8 bfv = *(const bf16x8*)(mybuf + l15 * GSTR + quad * 8 + tv * 32);
        acc = __builtin_amdgcn_mfma_f32_16x16x32_bf16(af[tv], bfv, acc, 0, 0, 0);
      }
      const int c = c0 + j;
      if (c == 0) {
#pragma unroll
        for (int r = 0; r < 4; ++r)
          if (l15 == quad * 4 + r) L[(quad * 4 + r) * LDW] = acc[r];
      } else {
        const int i = c - 1;
        if (quad == (i >> 2)) L[i * LDW + 1 + l15] = acc[i & 3];
      }
#pragma unroll
      for (int tv = 0; tv < 8; ++tv) g[tv] = gn[tv];
    }
    __syncthreads();
    if (threadIdx.x < 16) {
      float mainv = L[threadIdx.x * LDW];
      float mx = mainv;
      float nv[NEG_];
#pragma unroll
      for (int n = 0; n < NEG_; ++n) {
        nv[n] = L[threadIdx.x * LDW + 1 + n];
        mx = fmaxf(mx, nv[n]);
      }
      float num = __expf(mainv - mx);
      float se = num;
#pragma unroll
      for (int n = 0; n < NEG_; ++n) se += __expf(nv[n] - mx);
      Lk[kk * 14336 + m0 + threadIdx.x] = -logf(num / se + EPS_);
    }
    __syncthreads();   // L reused by next tile
  }
}

// ---- patchwise loss + counts (blocks 0..63); total loss (blocks 64..123) ----
__global__ __launch_bounds__(256) void finalize_pl(
    const float* __restrict__ Lk, float* __restrict__ out) {
  if (blockIdx.x < 64) {
    int idx = blockIdx.x * 256 + threadIdx.x;   // b*256 + h*16 + w
    int b = idx >> 8, h = (idx >> 4) & 15, w = idx & 15;
    float v = 0.f;
#pragma unroll
    for (int kk = 0; kk < PRED_; ++kk) {
      int off = kk + 2;
      if (h >= off)      v += Lk[kk * 14336 + ((h - off) * 16 + w) * 64 + b];
      if (h <= 15 - off) v += Lk[kk * 14336 + (h * 16 + w) * 64 + b];
    }
    out[1 + idx] = v;
    if (idx < 256) {
      int hh = idx >> 4;
      float cnt = 0.f;
#pragma unroll
      for (int off = 2; off <= 6; ++off)
        cnt += (hh >= off ? 1.f : 0.f) + (hh <= 15 - off ? 1.f : 0.f);
      out[1 + 16384 + idx] = cnt;
    }
  } else {
    // total loss: 60 blocks x 1024 elements, float4 loads, atomicAdd.
    __shared__ float red[4];
    const int cb = blockIdx.x - 64;             // 0..59
    const int kk = cb < 14 ? 0 : cb < 27 ? 1 : cb < 39 ? 2 : cb < 50 ? 3 : 4;
    const int s0 = kk == 0 ? 0 : kk == 1 ? 14 : kk == 2 ? 27 : kk == 3 ? 39 : 50;
    const float scale = 1.0f / (5120.0f * (float)(14 - kk));
    const int e = (cb - s0) * 1024 + threadIdx.x * 4;
    float4 v = *(const float4*)&Lk[kk * 14336 + e];
    float local = (v.x + v.y + v.z + v.w) * scale;
#pragma unroll
    for (int s = 32; s; s >>= 1) local += __shfl_down(local, s);
    if ((threadIdx.x & 63) == 0) red[threadIdx.x >> 6] = local;
    __syncthreads();
    if (threadIdx.x == 0)
      atomicAdd(out, red[0] + red[1] + red[2] + red[3]);
  }
}

extern "C" void kernel_launch(void* const* d_in, const int* in_sizes, int n_in,
                              void* d_out, int out_size, void* d_ws, size_t ws_size,
                              hipStream_t stream) {
  const float* z  = (const float*)d_in[0];
  const float* c  = (const float*)d_in[1];
  const float* Wk = (const float*)d_in[2];
  float* out = (float*)d_out;
  char* wsb = (char*)d_ws;
  unsigned short* Zp = (unsigned short*)(wsb);
  unsigned short* Cb = (unsigned short*)(wsb + 8388608);
  unsigned short* Wb = (unsigned short*)(wsb + 16777216);
  unsigned short* Cw = (unsigned short*)(wsb + 17432576);
  float*          Lk = (float*)(wsb + 54132736);

  prep_all<<<dim3(256, 8, 2), 256, 0, stream>>>(z, c, Wk, Zp, Cb, Wb, out);
  gemm_all<<<dim3(2, 112, PRED_), 256, 0, stream>>>(Cb, Wb, Cw);
  // persistent: 1024 blocks = exactly the 4-blocks/CU LDS cap on 256 CUs.
  score_all<<<1024, 256, 0, stream>>>(
      Cw, Zp, (const int*)d_in[3], (const int*)d_in[4], (const int*)d_in[5],
      (const int*)d_in[6], (const int*)d_in[7], Lk);
  finalize_pl<<<124, 256, 0, stream>>>(Lk, out);
}

// Round 9
// 154.216 us; speedup vs baseline: 1.2060x; 1.0207x over previous
//
#include <hip/hip_runtime.h>
#include <hip/hip_bf16.h>
#include <math.h>

#define NEG_ 16
#define PRED_ 5
#define EPS_ 1e-11f
#define LDW 18    // logit tile row stride (floats)
#define GSTR 272  // score LDS gather-row stride in shorts (544 B)
#define ASTR 72   // gemm LDS tile row stride in shorts (144 B, odd16 -> conflict-free b128)

typedef __attribute__((ext_vector_type(8))) short bf16x8;
typedef __attribute__((ext_vector_type(4))) float f32x4;

static __device__ __forceinline__ unsigned short f2bu(float f) {
  __hip_bfloat16 h = __float2bfloat16(f);
  return *(unsigned short*)&h;
}

// ws layout (bytes):
//   Zp bf16 [16384][256] : 0         rows = (h*16+w)*64+b; rows<2048 never touched
//   Cb bf16 [16384][256] : 8388608   rows>=14336 never touched
//   Wb bf16 [5][256][256]: 16777216  TRANSPOSED: Wb[k][o][i] = Wk[k][i][o]
//   Cw bf16 [5][14336][256]: 17432576  projected CONTEXT (Wk^T ctx)
//   Lk f32  [5][14336]   : 54132736  tails [Mk,14336) NEVER read -> no memset
// Purity: every read is of data written earlier in this launch.
// out[0] is re-zeroed by prep_all each launch (finalize atomicAdds into it).
//
// Request-rate model (validated R3/R4/R5/R6/R8): score time ~ vector-gather
// instruction count (~42 CU-cyc per 8-line gather inst). This version cuts
// requests 14%: the 16 Yc rows were gathered 4x (once per wave) -> now wave 0
// gathers them ONCE into gbuf[0], all waves read af from it. Chains
// rebalanced 4/5/4/4 so wv0 (Yc+4 chains) matches wv1 (5 chains).

// ---- prep: transpose z/c (+cast) with 128B-coalesced reads AND writes ----
__global__ __launch_bounds__(256) void prep_all(
    const float* __restrict__ z, const float* __restrict__ c,
    const float* __restrict__ Wk,
    unsigned short* __restrict__ Zp, unsigned short* __restrict__ Cb,
    unsigned short* __restrict__ Wb, float* __restrict__ out) {
  __shared__ float tile[32][65];   // [q][p]
  const int t = threadIdx.x;
  if (blockIdx.x == 0 && blockIdx.y == 0 && blockIdx.z == 0 && t == 0)
    out[0] = 0.f;   // total-loss accumulator, replay-safe zeroing
  if (blockIdx.y == 7) {
    // Wk TRANSPOSE (+cast): 5 matrices of 256x256, 32x32 LDS tiles.
    int ib = blockIdx.z * 256 + blockIdx.x;   // 0..511; need 320 = 5 k * 64 tiles
    if (ib < 320) {
      const int k = ib >> 6, tl = ib & 63;
      const int r0 = (tl >> 3) * 32, c0g = (tl & 7) * 32;
      const int tx = t & 31, ty = t >> 5;     // (32,8)
#pragma unroll
      for (int r = 0; r < 32; r += 8)
        tile[ty + r][tx] = Wk[k * 65536 + (r0 + ty + r) * 256 + c0g + tx];
      __syncthreads();
#pragma unroll
      for (int r = 0; r < 32; r += 8)   // Wb[k][o][i] = Wk[k][i][o]
        Wb[k * 65536 + (c0g + ty + r) * 256 + r0 + tx] = f2bu(tile[tx][ty + r]);
    }
    return;
  }
  const float* in = blockIdx.z ? c : z;
  unsigned short* out2 = blockIdx.z ? Cb : Zp;
  const int p0 = blockIdx.x * 64;                          // [0,16384)
  const int q0 = blockIdx.y * 32 + (blockIdx.z ? 0 : 32);  // z:[32,256) c:[0,224)
  const int tx = t & 31, ty = t >> 5;       // (32,8)
#pragma unroll
  for (int r = 0; r < 64; r += 8)
    tile[tx][ty + r] = in[(size_t)(p0 + ty + r) * 256 + q0 + tx];
  __syncthreads();
  const int pp = t & 63, wq = t >> 6;       // (64,4)
#pragma unroll
  for (int r = 0; r < 32; r += 4)
    out2[(size_t)(q0 + wq + r) * 16384 + p0 + pp] = f2bu(tile[wq + r][pp]);
}

// ---- LDS-staged MFMA GEMM: 128x128 tile, BK=64 ----
// Computes Cw_k[m][o] = sum_i Cb[m][i] * Wb_k[o][i] = (Wk^T ctx[m])[o].
__global__ __launch_bounds__(256) void gemm_all(
    const unsigned short* __restrict__ Cb, const unsigned short* __restrict__ Wb,
    unsigned short* __restrict__ Cw) {
  const int kk = blockIdx.z;
  const int Mk = (14 - kk) * 1024;
  const int m0b = blockIdx.y * 128;
  if (m0b >= Mk) return;
  const unsigned short* A = Cb;
  const unsigned short* Wm = Wb + (size_t)kk * 65536;
  unsigned short* Y = Cw + (size_t)kk * 14336 * 256;
  __shared__ unsigned short As[128 * ASTR];
  __shared__ unsigned short Bs[128 * ASTR];
  const int t = threadIdx.x;
  const int wid = t >> 6, lane = t & 63;
  const int wm = wid >> 1, wn = wid & 1;
  const int l15 = lane & 15, quad = lane >> 4;
  const int n0 = blockIdx.x * 128;
  const int srow = t >> 1, shalf = t & 1;
  const unsigned short* ga = A + (size_t)(m0b + srow) * 256 + shalf * 32;
  const unsigned short* gb = Wm + (size_t)(n0 + srow) * 256 + shalf * 32;
  unsigned short* wa = As + srow * ASTR + shalf * 32;
  unsigned short* wb = Bs + srow * ASTR + shalf * 32;
  f32x4 acc[4][4] = {};
  bf16x8 ra[4], rb[4];
#pragma unroll
  for (int cs = 0; cs < 4; ++cs) {
    ra[cs] = *(const bf16x8*)(ga + cs * 8);
    rb[cs] = *(const bf16x8*)(gb + cs * 8);
  }
#pragma unroll
  for (int ki = 0; ki < 4; ++ki) {
    __syncthreads();
#pragma unroll
    for (int cs = 0; cs < 4; ++cs) {
      *(bf16x8*)(wa + cs * 8) = ra[cs];
      *(bf16x8*)(wb + cs * 8) = rb[cs];
    }
    __syncthreads();
    if (ki < 3) {
      const int k1 = (ki + 1) * 64;
#pragma unroll
      for (int cs = 0; cs < 4; ++cs) {
        ra[cs] = *(const bf16x8*)(ga + k1 + cs * 8);
        rb[cs] = *(const bf16x8*)(gb + k1 + cs * 8);
      }
    }
#pragma unroll
    for (int ks = 0; ks < 2; ++ks) {
      bf16x8 af[4], bf[4];
#pragma unroll
      for (int tm = 0; tm < 4; ++tm)
        af[tm] = *(const bf16x8*)(As + (wm * 64 + tm * 16 + l15) * ASTR + ks * 32 + quad * 8);
#pragma unroll
      for (int tn = 0; tn < 4; ++tn)
        bf[tn] = *(const bf16x8*)(Bs + (wn * 64 + tn * 16 + l15) * ASTR + ks * 32 + quad * 8);
#pragma unroll
      for (int tm = 0; tm < 4; ++tm)
#pragma unroll
        for (int tn = 0; tn < 4; ++tn)
          acc[tm][tn] = __builtin_amdgcn_mfma_f32_16x16x32_bf16(
              af[tm], bf[tn], acc[tm][tn], 0, 0, 0);
    }
  }
#pragma unroll
  for (int tm = 0; tm < 4; ++tm)
#pragma unroll
    for (int tn = 0; tn < 4; ++tn)
#pragma unroll
      for (int r = 0; r < 4; ++r)
        Y[(size_t)(m0b + wm * 64 + tm * 16 + quad * 4 + r) * 256 +
          n0 + wn * 64 + tn * 16 + l15] = f2bu(acc[tm][tn][r]);
}

// ---- fused scoring: shared-Yc staging (1x instead of 4x), chains 4/5/4/4 ----
__global__ __launch_bounds__(256) void score_all(
    const unsigned short* __restrict__ Cw, const unsigned short* __restrict__ Zp,
    const int* __restrict__ r1, const int* __restrict__ r2,
    const int* __restrict__ r3, const int* __restrict__ r4,
    const int* __restrict__ r5, float* __restrict__ Lk) {
  __shared__ __align__(16) unsigned short gbuf[4][16 * GSTR];
  __shared__ float L[16 * LDW];
  const int wv = threadIdx.x >> 6, lane = threadIdx.x & 63;
  const int gid = blockIdx.x;
  int kk, base;
  if (gid < 896)       { kk = 0; base = 0; }
  else if (gid < 1728) { kk = 1; base = 896; }
  else if (gid < 2496) { kk = 2; base = 1728; }
  else if (gid < 3200) { kk = 3; base = 2496; }
  else                 { kk = 4; base = 3200; }
  const int Mk = (14 - kk) * 1024;
  const int m0 = (gid - base) * 16;
  const int* ridx = kk == 0 ? r1 : kk == 1 ? r2 : kk == 2 ? r3 : kk == 3 ? r4 : r5;
  const unsigned short* Yc = Cw + (size_t)kk * 14336 * 256;       // projected ctx
  const unsigned short* Z  = Zp + (size_t)(kk + 2) * 1024 * 256;  // raw z rows
  const int l15 = lane & 15, quad = lane >> 4;
  const int half = lane >> 5, ch = lane & 31;
  unsigned short* mybuf = gbuf[wv];

  auto gather = [&](const unsigned short* src, int ivv, bf16x8* dst) {
#pragma unroll
    for (int j = 0; j < 8; ++j) {
      int rlo = __shfl(ivv, 2 * j);
      int rhi = __shfl(ivv, 2 * j + 1);
      int row = half ? rhi : rlo;
      dst[j] = *(const bf16x8*)(src + (size_t)row * 256 + ch * 8);
    }
  };
  auto stage = [&](const bf16x8* g) {
#pragma unroll
    for (int j2 = 0; j2 < 8; ++j2)
      *(bf16x8*)(mybuf + (2 * j2 + half) * GSTR + ch * 8) = g[j2];
  };

  // chain assignment: wv0 carries Yc + chains 0..3; wv1: 4..8; wv2: 9..12;
  // wv3: 13..16 -> gathers per wave = 5/5/4/4 (balanced).
  const int c0 = (wv == 0) ? 0 : (wv == 1) ? 4 : (wv == 2) ? 9 : 13;
  const int nc = (wv == 1) ? 5 : 4;
  // chain indices upfront: ridx dword loads issue in parallel.
  int iv[5];
#pragma unroll
  for (int j = 0; j < 5; ++j) {
    if (j < nc) {
      const int c = c0 + j;
      if (c == 0) iv[j] = m0 + l15;
      else {
        int idx = ridx[(m0 + (c - 1)) * NEG_ + l15];
        iv[j] = idx < 0 ? 0 : (idx >= Mk ? Mk - 1 : idx);
      }
    } else iv[j] = 0;
  }

  // Issue first Z gather early (in flight across the Yc phase).
  bf16x8 g[8], gn[8];
  gather(Z, iv[0], g);

  // Wave 0 alone stages the 16 Yc rows into gbuf[0] (was: every wave, 4x
  // redundant requests). All waves then read their af fragments from it.
  if (wv == 0) {
    bf16x8 y[8];
    gather(Yc, m0 + l15, y);
    stage(y);            // mybuf == gbuf[0] for wv0
  }
  __syncthreads();
  bf16x8 af[8];
#pragma unroll
  for (int tv = 0; tv < 8; ++tv)
    af[tv] = *(const bf16x8*)(gbuf[0] + l15 * GSTR + quad * 8 + tv * 32);
  __syncthreads();   // af reads done before wv0 overwrites gbuf[0] with chains

  // depth-1 pipeline: gather(j+1) in flight while staging/MFMA chain j.
  for (int j = 0; j < nc; ++j) {
    if (j + 1 < nc) gather(Z, iv[j + 1], gn);
    stage(g);
    f32x4 acc = {};
#pragma unroll
    for (int tv = 0; tv < 8; ++tv) {
      bf16x8 bfv = *(const bf16x8*)(mybuf + l15 * GSTR + quad * 8 + tv * 32);
      acc = __builtin_amdgcn_mfma_f32_16x16x32_bf16(af[tv], bfv, acc, 0, 0, 0);
    }
    const int c = c0 + j;
    if (c == 0) {
#pragma unroll
      for (int r = 0; r < 4; ++r)
        if (l15 == quad * 4 + r) L[(quad * 4 + r) * LDW] = acc[r];
    } else {
      const int i = c - 1;
      if (quad == (i >> 2)) L[i * LDW + 1 + l15] = acc[i & 3];
    }
#pragma unroll
    for (int tv = 0; tv < 8; ++tv) g[tv] = gn[tv];
  }
  __syncthreads();
  if (threadIdx.x < 16) {
    float mainv = L[threadIdx.x * LDW];
    float mx = mainv;
    float nv[NEG_];
#pragma unroll
    for (int n = 0; n < NEG_; ++n) {
      nv[n] = L[threadIdx.x * LDW + 1 + n];
      mx = fmaxf(mx, nv[n]);
    }
    float num = __expf(mainv - mx);
    float se = num;
#pragma unroll
    for (int n = 0; n < NEG_; ++n) se += __expf(nv[n] - mx);
    Lk[kk * 14336 + m0 + threadIdx.x] = -logf(num / se + EPS_);
  }
}

// ---- patchwise loss + counts (blocks 0..63); total loss (blocks 64..123) ----
__global__ __launch_bounds__(256) void finalize_pl(
    const float* __restrict__ Lk, float* __restrict__ out) {
  if (blockIdx.x < 64) {
    int idx = blockIdx.x * 256 + threadIdx.x;   // b*256 + h*16 + w
    int b = idx >> 8, h = (idx >> 4) & 15, w = idx & 15;
    float v = 0.f;
#pragma unroll
    for (int kk = 0; kk < PRED_; ++kk) {
      int off = kk + 2;
      if (h >= off)      v += Lk[kk * 14336 + ((h - off) * 16 + w) * 64 + b];
      if (h <= 15 - off) v += Lk[kk * 14336 + (h * 16 + w) * 64 + b];
    }
    out[1 + idx] = v;
    if (idx < 256) {
      int hh = idx >> 4;
      float cnt = 0.f;
#pragma unroll
      for (int off = 2; off <= 6; ++off)
        cnt += (hh >= off ? 1.f : 0.f) + (hh <= 15 - off ? 1.f : 0.f);
      out[1 + 16384 + idx] = cnt;
    }
  } else {
    // total loss: 60 blocks x 1024 elements, float4 loads, atomicAdd.
    __shared__ float red[4];
    const int cb = blockIdx.x - 64;             // 0..59
    const int kk = cb < 14 ? 0 : cb < 27 ? 1 : cb < 39 ? 2 : cb < 50 ? 3 : 4;
    const int s0 = kk == 0 ? 0 : kk == 1 ? 14 : kk == 2 ? 27 : kk == 3 ? 39 : 50;
    const float scale = 1.0f / (5120.0f * (float)(14 - kk));
    const int e = (cb - s0) * 1024 + threadIdx.x * 4;
    float4 v = *(const float4*)&Lk[kk * 14336 + e];
    float local = (v.x + v.y + v.z + v.w) * scale;
#pragma unroll
    for (int s = 32; s; s >>= 1) local += __shfl_down(local, s);
    if ((threadIdx.x & 63) == 0) red[threadIdx.x >> 6] = local;
    __syncthreads();
    if (threadIdx.x == 0)
      atomicAdd(out, red[0] + red[1] + red[2] + red[3]);
  }
}

extern "C" void kernel_launch(void* const* d_in, const int* in_sizes, int n_in,
                              void* d_out, int out_size, void* d_ws, size_t ws_size,
                              hipStream_t stream) {
  const float* z  = (const float*)d_in[0];
  const float* c  = (const float*)d_in[1];
  const float* Wk = (const float*)d_in[2];
  float* out = (float*)d_out;
  char* wsb = (char*)d_ws;
  unsigned short* Zp = (unsigned short*)(wsb);
  unsigned short* Cb = (unsigned short*)(wsb + 8388608);
  unsigned short* Wb = (unsigned short*)(wsb + 16777216);
  unsigned short* Cw = (unsigned short*)(wsb + 17432576);
  float*          Lk = (float*)(wsb + 54132736);

  prep_all<<<dim3(256, 8, 2), 256, 0, stream>>>(z, c, Wk, Zp, Cb, Wb, out);
  gemm_all<<<dim3(2, 112, PRED_), 256, 0, stream>>>(Cb, Wb, Cw);
  score_all<<<3840, 256, 0, stream>>>(
      Cw, Zp, (const int*)d_in[3], (const int*)d_in[4], (const int*)d_in[5],
      (const int*)d_in[6], (const int*)d_in[7], Lk);
  finalize_pl<<<124, 256, 0, stream>>>(Lk, out);
}